// Round 19
// baseline (19.923 us; speedup 1.0000x reference)
//
#include <hip/hip_runtime.h>
#include <math.h>

// Voxelized chamfer via bf16 MFMA (32x32x16): 256 x 1024-thread blocks,
// 2 A-frags per wave (halved LDS-pipe traffic).
//   vox coords are integer-valued fp32, |v| <= ~160 -> EXACT in bf16.
//   A row i : {-2qx, -2qy, -2qz, 1, 1, 0...}   (-2q = exponent shift, exact)
//   B col j : { cx,   cy,   cz, yh, yl, 0...}  (yy = yh+yl exact bf16 split)
//   MFMA   -> yy_j - 2 q_i.c_j  directly; fp32 accum of exact ints < 2^20
//   -> exact. row-min + xx_i = chamfer row-min; 1 min3 / 2 evals.
//   loss = mean(row-mins, pred->gt) + mean(row-mins, gt->pred).
//
// R19 change vs R18 (16.76 us): k1 exec is LDS-pipe-dominated (16 waves x
// 32 ds_read_b128 x ~12cyc ~ 2.5 us/CU vs MFMA 0.4). Each wave now holds
// TWO A-frags (tile-pair tp = w>>3, queries tp*64..tp*64+63) and scans a
// 256-cand segment (s = w&7): 4 MFMA per 2 B-reads -> ds_read_b128 halves
// to 16/wave. MFMA/min3 counts unchanged. Staging identical to R18.
//
// k1: 256 blocks = (dir, batch, 128-query tile). Per chunk (2 x 2048 cands,
//     32 KB LDS): 1024 threads pack 2 points each via 3 float2 loads,
//     barrier, each wave: 4 x {2 ds_read_b128 + 4 MFMA_32x32x16 + 32 min3}.
//     Wrap-up: 5-level shfl min per tile, +xx, cross-wave LDS min by
//     combiner waves 0/8 -> partials[2*bid+tp].
// k2: 1 block, fixed-order tree sum of 512 partials, out[0] = sum * 2^-14.
//
// Exactness: staged values integer & bf16-exact (|v|<=512 even / <=2^17
// with <=9 sig bits); MFMA products <= ~2^17, 5-term fp32 accum exact; row
// mins exact ints; partial = sum of 64 ints < 2^25 exact; final fixed-order
// tree of 512 exact ints; SCALE = 2^-14 exact. vox keeps (c+off)*20.0f
// (R16 flip analysis); cvtpk packs (R17, exact on representable values).

typedef float  f32x16 __attribute__((ext_vector_type(16)));
typedef short  bf16x8 __attribute__((ext_vector_type(8)));

constexpr int NPTS   = 4096;
constexpr int BLK    = 1024;
constexpr int QPB    = 128;            // query rows per block (4 x 32-tiles)
constexpr int NTB    = NPTS / QPB;     // 32 row tiles per (dir, batch)
constexpr int BATCH  = 4;
constexpr int NBLOCKS = 2 * BATCH * NTB;   // 256
constexpr int CHUNK  = 2048;           // candidates staged per chunk
constexpr float FINF  = 3.402823466e38f;
constexpr float SCALE = 1.0f / 16384.0f;   // 1/(B*N) = 2^-14, exact

__device__ __forceinline__ float vox(float c, float off) {
    return truncf((c + off) * 20.0f);  // fast vox (R16 flip analysis)
}
__device__ __forceinline__ unsigned cvtpk(float lo, float hi) {
    unsigned r;                        // low16 = bf16(lo), high16 = bf16(hi)
    asm("v_cvt_pk_bf16_f32 %0, %1, %2" : "=v"(r) : "v"(lo), "v"(hi));
    return r;                          // exact: inputs exactly representable
}
__device__ __forceinline__ float min3f(float a, float b, float c) {
    return fminf(fminf(a, b), c);      // clang fuses to v_min3_f32
}
__device__ __forceinline__ int4 packB(float x, float y, float z) {
    const float yy = fmaf(z, z, fmaf(y, y, x * x));      // exact int
    const float hi = floorf(yy * 0.00390625f) * 256.0f;  // exact
    const float lo = yy - hi;                            // in [0,256)
    return make_int4((int)cvtpk(x, y),                   // k0:cx k1:cy
                     (int)cvtpk(z, hi),                  // k2:cz k3:yh
                     (int)cvtpk(lo, 0.0f),               // k4:yl k5:0
                     0);
}

__global__ __launch_bounds__(BLK, 4) void chamfer_rows_kernel(
    const float* __restrict__ preds,
    const float* __restrict__ gts,
    float* __restrict__ partials)      // [512]
{
    __shared__ int4  cfrag[CHUNK];     // candidate B-frags (32 KB)
    __shared__ int4  qfrag[QPB];       // query A-frags (prescaled -2, ones)
    __shared__ float qxx[QPB];         // query squared norms (exact ints)
    __shared__ float waveRow[16][64];  // per-wave row-mins (2 tiles each)

    const int t    = threadIdx.x;
    const int bid  = blockIdx.x;        // dir*128 + b*32 + tile
    const int dir  = bid >> 7;
    const int rem  = bid & 127;
    const int b    = rem >> 5;
    const int tile = rem & 31;
    const int w    = t >> 6;            // wave 0..15
    const int tp   = w >> 3;            // tile-pair 0/1 (queries tp*64 +..)
    const int s    = w & 7;             // candidate segment within chunk
    const int lane = t & 63;
    const int col  = lane & 31;         // A row / B col within 32-tile
    const bool lo_g = (lane < 32);      // k=0..7 carrier half

    const float* __restrict__ xb = (dir ? gts : preds) + (size_t)b * NPTS * 3;
    const float* __restrict__ yb = (dir ? preds : gts) + (size_t)b * NPTS * 3;

    // ---- stage this block's 128 query rows as A-frags ----
    if (t < QPB) {
        const int qi = tile * QPB + t;
        const float x = vox(xb[qi*3+0], 3.0f);
        const float y = vox(xb[qi*3+1], 3.0f);
        const float z = vox(xb[qi*3+2], 1.0f);
        qxx[t] = fmaf(z, z, fmaf(y, y, x * x));
        const float mx = -2.0f * x, my = -2.0f * y, mz = -2.0f * z; // exact
        qfrag[t] = make_int4((int)cvtpk(mx, my),         // k0 k1
                             (int)cvtpk(mz, 1.0f),       // k2 k3:1
                             (int)cvtpk(1.0f, 0.0f),     // k4:1 k5:0
                             0);
    }
    __syncthreads();

    // Two A fragments: tiles 2*tp and 2*tp+1 (lanes>=32 zeroed -> B's
    // k8..15 contribute exactly 0).
    bf16x8 afrag0, afrag1;
    {
        const int4 q0 = qfrag[tp * 64 + col];
        const int4 q1 = qfrag[tp * 64 + 32 + col];
        int4 a0 = { lo_g ? q0.x : 0, lo_g ? q0.y : 0, lo_g ? q0.z : 0, 0 };
        int4 a1 = { lo_g ? q1.x : 0, lo_g ? q1.y : 0, lo_g ? q1.z : 0, 0 };
        afrag0 = __builtin_bit_cast(bf16x8, a0);
        afrag1 = __builtin_bit_cast(bf16x8, a1);
    }

    f32x16 rm0, rm1;
    #pragma unroll
    for (int i = 0; i < 16; ++i) { rm0[i] = FINF; rm1[i] = FINF; }
    const f32x16 zero = {};

    const float2* __restrict__ yb2 = (const float2*)yb;

    // ---- 2 chunks: pack 2048 candidates (2/thread), barrier, scan ----
    #pragma unroll 1
    for (int cc = 0; cc < 2; ++cc) {
        if (cc) __syncthreads();           // previous chunk's readers done
        {
            const int p0 = t * 2;
            const int fi = cc * 3072 + t * 3;
            const float2 r0 = yb2[fi + 0];
            const float2 r1 = yb2[fi + 1];
            const float2 r2 = yb2[fi + 2];
            cfrag[p0+0] = packB(vox(r0.x,3.f), vox(r0.y,3.f), vox(r1.x,1.f));
            cfrag[p0+1] = packB(vox(r1.y,3.f), vox(r2.x,3.f), vox(r2.y,1.f));
        }
        __syncthreads();

        // 256-cand segment: 4 x {2 ds_read_b128, 4 MFMA, 32 min3}
        const int4* __restrict__ bbase = &cfrag[s * 256 + col];
        #pragma unroll
        for (int jp = 0; jp < 4; ++jp) {
            const bf16x8 bfa = __builtin_bit_cast(bf16x8, bbase[jp * 64]);
            const bf16x8 bfb = __builtin_bit_cast(bf16x8, bbase[jp * 64 + 32]);
            const f32x16 d0a = __builtin_amdgcn_mfma_f32_32x32x16_bf16(
                afrag0, bfa, zero, 0, 0, 0);
            const f32x16 d0b = __builtin_amdgcn_mfma_f32_32x32x16_bf16(
                afrag0, bfb, zero, 0, 0, 0);
            const f32x16 d1a = __builtin_amdgcn_mfma_f32_32x32x16_bf16(
                afrag1, bfa, zero, 0, 0, 0);
            const f32x16 d1b = __builtin_amdgcn_mfma_f32_32x32x16_bf16(
                afrag1, bfb, zero, 0, 0, 0);
            #pragma unroll
            for (int i = 0; i < 16; ++i) {
                rm0[i] = min3f(rm0[i], d0a[i], d0b[i]);
                rm1[i] = min3f(rm1[i], d1a[i], d1b[i]);
            }
        }
    }

    // ---- row-min wrap-up: min over 32 cols (5-level shfl in halves) ----
    const int hi4 = (lane >> 5) * 4;
    #pragma unroll
    for (int i = 0; i < 16; ++i) {
        float v0 = rm0[i], v1 = rm1[i];
        v0 = fminf(v0, __shfl_xor(v0, 1, 64));
        v1 = fminf(v1, __shfl_xor(v1, 1, 64));
        v0 = fminf(v0, __shfl_xor(v0, 2, 64));
        v1 = fminf(v1, __shfl_xor(v1, 2, 64));
        v0 = fminf(v0, __shfl_xor(v0, 4, 64));
        v1 = fminf(v1, __shfl_xor(v1, 4, 64));
        v0 = fminf(v0, __shfl_xor(v0, 8, 64));
        v1 = fminf(v1, __shfl_xor(v1, 8, 64));
        v0 = fminf(v0, __shfl_xor(v0, 16, 64));
        v1 = fminf(v1, __shfl_xor(v1, 16, 64));
        const int r = (i & 3) + 8 * (i >> 2) + hi4;   // C/D map (m74/m101)
        if (col == 0) {
            waveRow[w][r]      = v0;       // tile 2*tp,   query r
            waveRow[w][32 + r] = v1;       // tile 2*tp+1, query r
        }
    }
    __syncthreads();

    // ---- combiner waves 0 and 8: 64 queries each, min over 8 waves ----
    if (s == 0) {                       // waves 0 (tp=0) and 8 (tp=1)
        const int wbase = tp * 8;
        float m = waveRow[wbase][lane];
        #pragma unroll
        for (int k = 1; k < 8; ++k)
            m = fminf(m, waveRow[wbase + k][lane]);
        float v = m + qxx[tp * 64 + lane];     // exact int add
        #pragma unroll
        for (int o = 32; o >= 1; o >>= 1) v += __shfl_xor(v, o, 64);
        if (lane == 0) partials[bid * 2 + tp] = v;  // exact int sum of 64
    }
}

// ---------------- k2: tiny fixed-order final reduce ----------------
__global__ __launch_bounds__(256) void chamfer_finish_kernel(
    const float* __restrict__ partials, float* __restrict__ out)
{
    __shared__ float s1[256];
    const int t = threadIdx.x;
    s1[t] = partials[t] + partials[t + 256];   // fixed order
    __syncthreads();
    for (int k = 128; k > 0; k >>= 1) {
        if (t < k) s1[t] += s1[t + k];
        __syncthreads();
    }
    if (t == 0) out[0] = s1[0] * SCALE;    // overwrite: no init needed
}

extern "C" void kernel_launch(void* const* d_in, const int* in_sizes, int n_in,
                              void* d_out, int out_size, void* d_ws, size_t ws_size,
                              hipStream_t stream)
{
    const float* preds = (const float*)d_in[0];
    const float* gts   = (const float*)d_in[1];
    float* out = (float*)d_out;
    float* partials = (float*)d_ws;        // 512 floats

    chamfer_rows_kernel<<<NBLOCKS, BLK, 0, stream>>>(preds, gts, partials);
    chamfer_finish_kernel<<<1, 256, 0, stream>>>(partials, out);
}

// Round 20
// 16.877 us; speedup vs baseline: 1.1805x; 1.1805x over previous
//
#include <hip/hip_runtime.h>
#include <math.h>

// [REVERT to R18 — session best: 16.76 us, absmax 0.]
// R19's dual-A-frag variant regressed (19.9 us): 4 concurrent f32x16 MFMA
// dests (64 VGPR) + 2 accumulators under the launch_bounds(1024,4) 128-VGPR
// cap -> spill/serialization outweighed the halved ds_read traffic.
//
// Voxelized chamfer via bf16 MFMA (32x32x16): 256 x 1024-thread blocks.
//   vox coords are integer-valued fp32, |v| <= ~160 -> EXACT in bf16.
//   A row i : {-2qx, -2qy, -2qz, 1, 1, 0...}   (-2q = exponent shift, exact)
//   B col j : { cx,   cy,   cz, yh, yl, 0...}  (yy = yh+yl exact bf16 split)
//   MFMA   -> yy_j - 2 q_i.c_j  directly; 16-term fp32 accum of exact ints
//   < 2^20 -> exact. row-min + xx_i = chamfer row-min; 1 min3 / 2 evals.
//   loss = mean(row-mins, pred->gt) + mean(row-mins, gt->pred).
//
// k1: 256 blocks = (dir, batch, 128-query tile), 16 waves/CU. Per chunk
//     (2 x 2048 cands, 32 KB LDS): 1024 threads pack 2 points each via 3
//     float2 loads (fast vox (c+off)*20, R16 analysis; cvt_pk_bf16 packs,
//     R17), barrier, each wave scans its 512-cand segment for its 32-query
//     tile: 8 x {2 ds_read_b128 + 2 MFMA_32x32x16 + 16 min3}. Wrap-up:
//     5-level shfl min, +xx, cross-wave LDS min -> partials[4*bid+g].
// k2: 1 block, fixed-order tree sum of 1024 partials, out[0] = sum * 2^-14.
//
// Exactness: staged values integer & bf16-exact (|v|<=512 even / <=2^17
// with <=9 sig bits); MFMA products <= ~2^17, 5-term fp32 accum exact; row
// mins exact ints; partial = sum of 32 ints < 2^24 exact; final fixed-order
// tree of 1024 exact ints; SCALE = 2^-14 exact.

typedef float  f32x16 __attribute__((ext_vector_type(16)));
typedef short  bf16x8 __attribute__((ext_vector_type(8)));

constexpr int NPTS   = 4096;
constexpr int BLK    = 1024;
constexpr int QPB    = 128;            // query rows per block (4 x 32-tiles)
constexpr int NTB    = NPTS / QPB;     // 32 row tiles per (dir, batch)
constexpr int BATCH  = 4;
constexpr int NBLOCKS = 2 * BATCH * NTB;   // 256
constexpr int CHUNK  = 2048;           // candidates staged per chunk
constexpr float FINF  = 3.402823466e38f;
constexpr float SCALE = 1.0f / 16384.0f;   // 1/(B*N) = 2^-14, exact

__device__ __forceinline__ float vox(float c, float off) {
    return truncf((c + off) * 20.0f);  // fast vox (R16 flip analysis)
}
__device__ __forceinline__ unsigned cvtpk(float lo, float hi) {
    unsigned r;                        // low16 = bf16(lo), high16 = bf16(hi)
    asm("v_cvt_pk_bf16_f32 %0, %1, %2" : "=v"(r) : "v"(lo), "v"(hi));
    return r;                          // exact: inputs exactly representable
}
__device__ __forceinline__ float min3f(float a, float b, float c) {
    return fminf(fminf(a, b), c);      // clang fuses to v_min3_f32
}
__device__ __forceinline__ int4 packB(float x, float y, float z) {
    const float yy = fmaf(z, z, fmaf(y, y, x * x));      // exact int
    const float hi = floorf(yy * 0.00390625f) * 256.0f;  // exact
    const float lo = yy - hi;                            // in [0,256)
    return make_int4((int)cvtpk(x, y),                   // k0:cx k1:cy
                     (int)cvtpk(z, hi),                  // k2:cz k3:yh
                     (int)cvtpk(lo, 0.0f),               // k4:yl k5:0
                     0);
}

__global__ __launch_bounds__(BLK, 4) void chamfer_rows_kernel(
    const float* __restrict__ preds,
    const float* __restrict__ gts,
    float* __restrict__ partials)      // [1024]
{
    __shared__ int4  cfrag[CHUNK];     // candidate B-frags (32 KB)
    __shared__ int4  qfrag[QPB];       // query A-frags (prescaled -2, ones)
    __shared__ float qxx[QPB];         // query squared norms (exact ints)
    __shared__ float waveRow[16][32];

    const int t    = threadIdx.x;
    const int bid  = blockIdx.x;        // dir*128 + b*32 + tile
    const int dir  = bid >> 7;
    const int rem  = bid & 127;
    const int b    = rem >> 5;
    const int tile = rem & 31;
    const int w    = t >> 6;            // wave 0..15
    const int g    = w >> 2;            // tile-group 0..3
    const int wsub = w & 3;             // candidate segment within chunk
    const int lane = t & 63;
    const int col  = lane & 31;         // A row / B col within 32-tile
    const bool lo_g = (lane < 32);      // k=0..7 carrier half

    const float* __restrict__ xb = (dir ? gts : preds) + (size_t)b * NPTS * 3;
    const float* __restrict__ yb = (dir ? preds : gts) + (size_t)b * NPTS * 3;

    // ---- stage this block's 128 query rows as A-frags ----
    if (t < QPB) {
        const int qi = tile * QPB + t;
        const float x = vox(xb[qi*3+0], 3.0f);
        const float y = vox(xb[qi*3+1], 3.0f);
        const float z = vox(xb[qi*3+2], 1.0f);
        qxx[t] = fmaf(z, z, fmaf(y, y, x * x));
        const float mx = -2.0f * x, my = -2.0f * y, mz = -2.0f * z; // exact
        qfrag[t] = make_int4((int)cvtpk(mx, my),         // k0 k1
                             (int)cvtpk(mz, 1.0f),       // k2 k3:1
                             (int)cvtpk(1.0f, 0.0f),     // k4:1 k5:0
                             0);
    }
    __syncthreads();

    // A fragment for this wave's 32-query tile (lanes>=32 zeroed -> B's
    // k8..15 contribute exactly 0).
    bf16x8 afrag;
    {
        const int4 qv = qfrag[g * 32 + col];
        int4 ai = { lo_g ? qv.x : 0, lo_g ? qv.y : 0, lo_g ? qv.z : 0, 0 };
        afrag = __builtin_bit_cast(bf16x8, ai);
    }

    f32x16 rm;
    #pragma unroll
    for (int i = 0; i < 16; ++i) rm[i] = FINF;
    const f32x16 zero = {};

    const float2* __restrict__ yb2 = (const float2*)yb;

    // ---- 2 chunks: pack 2048 candidates (2/thread), barrier, scan ----
    #pragma unroll 1
    for (int cc = 0; cc < 2; ++cc) {
        if (cc) __syncthreads();           // previous chunk's readers done
        {
            const int p0 = t * 2;
            const int fi = cc * 3072 + t * 3;
            const float2 r0 = yb2[fi + 0];
            const float2 r1 = yb2[fi + 1];
            const float2 r2 = yb2[fi + 2];
            cfrag[p0+0] = packB(vox(r0.x,3.f), vox(r0.y,3.f), vox(r1.x,1.f));
            cfrag[p0+1] = packB(vox(r1.y,3.f), vox(r2.x,3.f), vox(r2.y,1.f));
        }
        __syncthreads();

        const int4* __restrict__ bbase = &cfrag[wsub * 512 + col];
        #pragma unroll
        for (int jp = 0; jp < 8; ++jp) {
            const bf16x8 bfa = __builtin_bit_cast(bf16x8, bbase[jp * 64]);
            const bf16x8 bfb = __builtin_bit_cast(bf16x8, bbase[jp * 64 + 32]);
            const f32x16 dA = __builtin_amdgcn_mfma_f32_32x32x16_bf16(
                afrag, bfa, zero, 0, 0, 0);
            const f32x16 dB = __builtin_amdgcn_mfma_f32_32x32x16_bf16(
                afrag, bfb, zero, 0, 0, 0);
            #pragma unroll
            for (int i = 0; i < 16; ++i)
                rm[i] = min3f(rm[i], dA[i], dB[i]);
        }
    }

    // ---- row-min wrap-up: min over 32 cols (5-level shfl in halves) ----
    const int hi4 = (lane >> 5) * 4;
    #pragma unroll
    for (int i = 0; i < 16; ++i) {
        float v = rm[i];
        v = fminf(v, __shfl_xor(v, 1, 64));
        v = fminf(v, __shfl_xor(v, 2, 64));
        v = fminf(v, __shfl_xor(v, 4, 64));
        v = fminf(v, __shfl_xor(v, 8, 64));
        v = fminf(v, __shfl_xor(v, 16, 64));
        const int r = (i & 3) + 8 * (i >> 2) + hi4;   // C/D map (m74/m101)
        if (col == 0) waveRow[w][r] = v + qxx[g * 32 + r];
    }
    __syncthreads();

    // ---- per-tile-group combine: waves 0/4/8/12 ----
    if ((w & 3) == 0) {
        float s = 0.0f;
        if (lane < 32) {
            s = fminf(fminf(waveRow[w + 0][lane], waveRow[w + 1][lane]),
                      fminf(waveRow[w + 2][lane], waveRow[w + 3][lane]));
        }
        #pragma unroll
        for (int o = 32; o >= 1; o >>= 1) s += __shfl_xor(s, o, 64);
        if (lane == 0) partials[bid * 4 + g] = s;   // exact int sum of 32
    }
}

// ---------------- k2: tiny fixed-order final reduce ----------------
__global__ __launch_bounds__(256) void chamfer_finish_kernel(
    const float* __restrict__ partials, float* __restrict__ out)
{
    __shared__ float s1[256];
    const int t = threadIdx.x;
    s1[t] = (partials[t] + partials[t + 256])
          + (partials[t + 512] + partials[t + 768]);   // fixed order
    __syncthreads();
    for (int k = 128; k > 0; k >>= 1) {
        if (t < k) s1[t] += s1[t + k];
        __syncthreads();
    }
    if (t == 0) out[0] = s1[0] * SCALE;    // overwrite: no init needed
}

extern "C" void kernel_launch(void* const* d_in, const int* in_sizes, int n_in,
                              void* d_out, int out_size, void* d_ws, size_t ws_size,
                              hipStream_t stream)
{
    const float* preds = (const float*)d_in[0];
    const float* gts   = (const float*)d_in[1];
    float* out = (float*)d_out;
    float* partials = (float*)d_ws;        // 1024 floats

    chamfer_rows_kernel<<<NBLOCKS, BLK, 0, stream>>>(preds, gts, partials);
    chamfer_finish_kernel<<<1, 256, 0, stream>>>(partials, out);
}